// Round 1
// baseline (153.402 us; speedup 1.0000x reference)
//
#include <hip/hip_runtime.h>
#include <hip/hip_bf16.h>
#include <stdint.h>

// Problem constants
#define BATCH 64
#define CH 3
#define HW 224
#define PP 7
#define GHW 32           // 32x32 patches
#define PD 147           // 7*7*3
#define DIM 1024
#define NTOK 65536       // 64 * 1024 tokens
#define KPAD 192         // 147 padded to 6*32

typedef _Float16 half8 __attribute__((ext_vector_type(8)));
typedef float f32x4 __attribute__((ext_vector_type(4)));

// ---------------- positional embedding table [1024][1024] ----------------
__global__ void pe_gen(float* __restrict__ pe) {
    int id = blockIdx.x * 256 + threadIdx.x;      // < 1048576
    int n = id >> 10, d = id & 1023;
    int yg = n >> 5, xg = n & 31;
    int quad = d >> 8, k = d & 255;
    // omega = 10000^(-k/255) = 2^(-k/255 * log2(10000))
    float omega = exp2f(-13.287712379549449f * (float)k * (1.0f / 255.0f));
    float coord = (quad < 2) ? (float)xg : (float)yg;
    float arg = coord * omega;
    pe[id] = (quad & 1) ? cosf(arg) : sinf(arg);
}

// ---------------- mean|W| partial sums (deterministic) ----------------
__global__ void wabs(const float* __restrict__ W, float* __restrict__ part) {
    __shared__ float red[256];
    int t = threadIdx.x;
    int base = blockIdx.x * 1024;                 // 147 blocks * 1024 = 150528
    float s = fabsf(W[base + t]) + fabsf(W[base + t + 256]) +
              fabsf(W[base + t + 512]) + fabsf(W[base + t + 768]);
    red[t] = s;
    __syncthreads();
    for (int off = 128; off > 0; off >>= 1) {
        if (t < off) red[t] += red[t + off];
        __syncthreads();
    }
    if (t == 0) part[blockIdx.x] = red[0];
}

__global__ void wscale(const float* __restrict__ part, float* __restrict__ swbuf) {
    float s = 0.f;
    for (int i = 0; i < 147; i++) s += part[i];   // fixed order -> deterministic
    float mean = s * (1.0f / 150528.0f);
    float m = fmaxf(mean, 1e-5f);
    swbuf[0] = 1.0f / m;   // s_w
    swbuf[1] = m;          // 1/s_w (dequant scale)
}

// ---------------- ternary weight quant, pre-swizzled to MFMA B layout ----------------
// Wq layout: [kk(6)][c(4)][d(1024)][8 halves], k = kk*32 + c*8 + j
__global__ void wquant(const float* __restrict__ W, const float* __restrict__ swbuf,
                       _Float16* __restrict__ Wq) {
    int e = blockIdx.x * 256 + threadIdx.x;       // < 196608 = 1024*192
    int d = e / 192, k = e % 192;
    float t = 0.f;
    if (k < 147) {
        float sw = swbuf[0];
        t = rintf(W[d * 147 + k] * sw);
        t = fminf(fmaxf(t, -1.f), 1.f);
    }
    int kk = k >> 5, c = (k >> 3) & 3, j = k & 7;
    Wq[((((kk * 4 + c) << 10) | d) << 3) | j] = (_Float16)t;
}

// ---------------- patchify + LN1 + per-token absmax int8 fake-quant ----------------
// A layout: [rowblk(1024)][c24(24)][r(64)][8 halves]  (block-contiguous for GEMM)
__global__ __launch_bounds__(256) void apack(const float* __restrict__ x,
                                             const float* __restrict__ g1,
                                             const float* __restrict__ b1,
                                             _Float16* __restrict__ Aq,
                                             float* __restrict__ inv_sx) {
    int wave = threadIdx.x >> 6, lane = threadIdx.x & 63;
    int t = blockIdx.x * 4 + wave;                // token 0..65535
    int b = t >> 10, n = t & 1023, gh = n >> 5, gw = n & 31;
    const float* xb = x + (size_t)b * (CH * HW * HW);

    float v[3];
    float sum = 0.f, sq = 0.f;
#pragma unroll
    for (int i = 0; i < 3; i++) {
        int k = lane + 64 * i;
        float val = 0.f;
        if (k < 147) {
            int c = k % 3, pp = k / 3, p1 = pp / 7, p2 = pp % 7;
            val = xb[((c * HW) + gh * 7 + p1) * HW + gw * 7 + p2];
        }
        v[i] = val;
        sum += val; sq += val * val;
    }
#pragma unroll
    for (int m = 1; m < 64; m <<= 1) {
        sum += __shfl_xor(sum, m);
        sq  += __shfl_xor(sq, m);
    }
    float mu = sum * (1.0f / 147.0f);
    float var = sq * (1.0f / 147.0f) - mu * mu;
    float rstd = rsqrtf(var + 1e-5f);

    float amax = 0.f;
#pragma unroll
    for (int i = 0; i < 3; i++) {
        int k = lane + 64 * i;
        if (k < 147) {
            v[i] = (v[i] - mu) * rstd * g1[k] + b1[k];
            amax = fmaxf(amax, fabsf(v[i]));
        } else {
            v[i] = 0.f;
        }
    }
#pragma unroll
    for (int m = 1; m < 64; m <<= 1) amax = fmaxf(amax, __shfl_xor(amax, m));

    float mx = fmaxf(amax, 1e-5f);
    float sx = 127.0f / mx;
    int blkRow = t >> 6, r = t & 63;
#pragma unroll
    for (int i = 0; i < 3; i++) {
        int k = lane + 64 * i;
        float q = 0.f;
        if (k < 147) q = fminf(fmaxf(rintf(v[i] * sx), -128.f), 127.f);
        Aq[(((size_t)blkRow * 24 + (k >> 3)) * 64 + r) * 8 + (k & 7)] = (_Float16)q;
    }
    if (lane == 0) inv_sx[t] = mx * (1.0f / 127.0f);
}

// ---------------- fused GEMM (int-exact via f16 MFMA) + bias + LN2 + posemb ----------------
// grid: 1024 blocks (64 rows each), 1024 threads = 16 waves (4 wm x 4 wn)
// wave (wm,wn): rows [wm*16,+16), cols [wn*256,+256) -> 16 accumulators of 16x16
__global__ __launch_bounds__(1024, 4) void gemm_ln(
    const _Float16* __restrict__ Aq, const _Float16* __restrict__ Wq,
    const float* __restrict__ inv_sx, const float* __restrict__ swbuf,
    const float* __restrict__ bproj, const float* __restrict__ g2,
    const float* __restrict__ b2, const float* __restrict__ pe,
    float* __restrict__ out) {
    extern __shared__ _Float16 Blds[];            // 64 KB: [c(4)][d(1024)][8]
    __shared__ float stats[4 * 16 * 4 * 2];       // [wm][rloc][wn][{sum,sumsq}]

    int tid = threadIdx.x;
    int wave = tid >> 6, lane = tid & 63;
    int wm = wave >> 2, wn = wave & 3;
    int l15 = lane & 15, lg = lane >> 4;
    int blk = blockIdx.x;

    f32x4 acc[16];
#pragma unroll
    for (int i = 0; i < 16; i++) acc[i] = (f32x4)0.f;

    const half8* Ablk = (const half8*)(Aq + (size_t)blk * (24 * 64 * 8));
    const half8* BsrcAll = (const half8*)Wq;
    half8* Bl = (half8*)Blds;
    float inv_sw = swbuf[1];

    for (int kk = 0; kk < 6; kk++) {
        // stage B k-slice (64 KB) into LDS: 4096 chunks of 16B
        half8 t0 = BsrcAll[kk * 4096 + tid];
        half8 t1 = BsrcAll[kk * 4096 + tid + 1024];
        half8 t2 = BsrcAll[kk * 4096 + tid + 2048];
        half8 t3 = BsrcAll[kk * 4096 + tid + 3072];
        Bl[tid] = t0; Bl[tid + 1024] = t1; Bl[tid + 2048] = t2; Bl[tid + 3072] = t3;
        __syncthreads();

        // A fragment: row = wm*16 + l15, k = kk*32 + lg*8 + j
        half8 a = Ablk[(kk * 4 + lg) * 64 + wm * 16 + l15];
#pragma unroll
        for (int n = 0; n < 16; n++) {
            half8 bf = Bl[lg * 1024 + wn * 256 + n * 16 + l15];
            acc[n] = __builtin_amdgcn_mfma_f32_16x16x32_f16(a, bf, acc[n], 0, 0, 0);
        }
        __syncthreads();
    }

    // -------- epilogue: scale + bias, then LN over the 1024 cols of each row --------
    float scale[4];
#pragma unroll
    for (int rr = 0; rr < 4; rr++) {
        int row = blk * 64 + wm * 16 + lg * 4 + rr;
        scale[rr] = inv_sx[row] * inv_sw;
    }
    int col0 = wn * 256 + l15;
    float s[4] = {0.f, 0.f, 0.f, 0.f}, q[4] = {0.f, 0.f, 0.f, 0.f};
#pragma unroll
    for (int n = 0; n < 16; n++) {
        int col = col0 + n * 16;
        float bp = bproj[col];
#pragma unroll
        for (int rr = 0; rr < 4; rr++) {
            float v = acc[n][rr] * scale[rr] + bp;
            acc[n][rr] = v;
            s[rr] += v; q[rr] += v * v;
        }
    }
#pragma unroll
    for (int m = 1; m < 16; m <<= 1) {
#pragma unroll
        for (int rr = 0; rr < 4; rr++) {
            s[rr] += __shfl_xor(s[rr], m);
            q[rr] += __shfl_xor(q[rr], m);
        }
    }
    if (l15 == 0) {
#pragma unroll
        for (int rr = 0; rr < 4; rr++) {
            int rloc = lg * 4 + rr;
            stats[((wm * 16 + rloc) * 4 + wn) * 2 + 0] = s[rr];
            stats[((wm * 16 + rloc) * 4 + wn) * 2 + 1] = q[rr];
        }
    }
    __syncthreads();

    float mean[4], rstd[4];
#pragma unroll
    for (int rr = 0; rr < 4; rr++) {
        int rloc = lg * 4 + rr;
        float st = 0.f, qt = 0.f;
#pragma unroll
        for (int w = 0; w < 4; w++) {
            st += stats[((wm * 16 + rloc) * 4 + w) * 2 + 0];
            qt += stats[((wm * 16 + rloc) * 4 + w) * 2 + 1];
        }
        float mu = st * (1.0f / 1024.0f);
        mean[rr] = mu;
        rstd[rr] = rsqrtf(qt * (1.0f / 1024.0f) - mu * mu + 1e-5f);
    }

#pragma unroll
    for (int n = 0; n < 16; n++) {
        int col = col0 + n * 16;
        float gg = g2[col], bb = b2[col];
#pragma unroll
        for (int rr = 0; rr < 4; rr++) {
            int row = blk * 64 + wm * 16 + lg * 4 + rr;
            int nimg = row & 1023;
            float o = (acc[n][rr] - mean[rr]) * rstd[rr] * gg + bb + pe[nimg * 1024 + col];
            out[(size_t)row * 1024 + col] = o;
        }
    }
}

extern "C" void kernel_launch(void* const* d_in, const int* in_sizes, int n_in,
                              void* d_out, int out_size, void* d_ws, size_t ws_size,
                              hipStream_t stream) {
    const float* x     = (const float*)d_in[0];
    const float* ln1_g = (const float*)d_in[1];
    const float* ln1_b = (const float*)d_in[2];
    const float* W     = (const float*)d_in[3];
    const float* bproj = (const float*)d_in[4];
    const float* ln2_g = (const float*)d_in[5];
    const float* ln2_b = (const float*)d_in[6];
    float* out = (float*)d_out;

    // workspace layout
    char* ws = (char*)d_ws;
    float*    pe     = (float*)ws;                                   // 4 MB
    _Float16* Aq     = (_Float16*)(ws + (4u << 20));                 // 25,165,824 B
    float*    inv_sx = (float*)(ws + (4u << 20) + 25165824u);        // 262,144 B
    _Float16* Wq     = (_Float16*)(ws + (4u << 20) + 25165824u + 262144u); // 393,216 B
    float*    part   = (float*)(ws + (4u << 20) + 25165824u + 262144u + 393216u);
    float*    swbuf  = part + 160;

    pe_gen<<<4096, 256, 0, stream>>>(pe);
    wabs<<<147, 256, 0, stream>>>(W, part);
    wscale<<<1, 1, 0, stream>>>(part, swbuf);
    wquant<<<768, 256, 0, stream>>>(W, swbuf, Wq);
    apack<<<16384, 256, 0, stream>>>(x, ln1_g, ln1_b, Aq, inv_sx);
    gemm_ln<<<1024, 1024, 65536, stream>>>(Aq, Wq, inv_sx, swbuf, bproj,
                                           ln2_g, ln2_b, pe, out);
}

// Round 2
// 134.678 us; speedup vs baseline: 1.1390x; 1.1390x over previous
//
#include <hip/hip_runtime.h>
#include <hip/hip_bf16.h>
#include <stdint.h>

// Problem constants
#define BATCH 64
#define CH 3
#define HW 224
#define PP 7
#define GHW 32           // 32x32 patches
#define PD 147           // 7*7*3
#define DIM 1024
#define NTOK 65536       // 64 * 1024 tokens

typedef _Float16 half8 __attribute__((ext_vector_type(8)));
typedef float f32x4 __attribute__((ext_vector_type(4)));
typedef float f32x4b __attribute__((ext_vector_type(4)));

// ---------------- positional embedding table [1024][1024] ----------------
__global__ void pe_gen(float* __restrict__ pe) {
    int id = blockIdx.x * 256 + threadIdx.x;      // < 1048576
    int n = id >> 10, d = id & 1023;
    int yg = n >> 5, xg = n & 31;
    int quad = d >> 8, k = d & 255;
    float omega = exp2f(-13.287712379549449f * (float)k * (1.0f / 255.0f));
    float coord = (quad < 2) ? (float)xg : (float)yg;
    float arg = coord * omega;
    pe[id] = (quad & 1) ? cosf(arg) : sinf(arg);
}

// ---------------- mean|W| partial sums (deterministic) ----------------
__global__ void wabs(const float* __restrict__ W, float* __restrict__ part) {
    __shared__ float red[256];
    int t = threadIdx.x;
    int base = blockIdx.x * 1024;                 // 147 blocks * 1024 = 150528
    float s = fabsf(W[base + t]) + fabsf(W[base + t + 256]) +
              fabsf(W[base + t + 512]) + fabsf(W[base + t + 768]);
    red[t] = s;
    __syncthreads();
    for (int off = 128; off > 0; off >>= 1) {
        if (t < off) red[t] += red[t + off];
        __syncthreads();
    }
    if (t == 0) part[blockIdx.x] = red[0];
}

// ---------------- ternary weight quant (scale folded in), MFMA B layout ----------------
// Wq layout: [c24 = k>>3][d(1024)][j = k&7], k padded to 192
__global__ void wquant(const float* __restrict__ W, const float* __restrict__ part,
                       float* __restrict__ swbuf, _Float16* __restrict__ Wq) {
    __shared__ float red[256];
    int tid = threadIdx.x;
    red[tid] = (tid < 147) ? part[tid] : 0.f;
    __syncthreads();
    for (int off = 128; off > 0; off >>= 1) {
        if (tid < off) red[tid] += red[tid + off];
        __syncthreads();
    }
    float m = fmaxf(red[0] * (1.0f / 150528.0f), 1e-5f);
    float sw = 1.0f / m;
    if (blockIdx.x == 0 && tid == 0) swbuf[0] = m;   // dequant scale for gemm

    int e = blockIdx.x * 256 + tid;               // < 196608 = 1024*192
    int d = e / 192, k = e % 192;
    float t = 0.f;
    if (k < 147) {
        t = rintf(W[d * 147 + k] * sw);
        t = fminf(fmaxf(t, -1.f), 1.f);
    }
    Wq[((((k >> 3) << 10) | d) << 3) | (k & 7)] = (_Float16)t;
}

// ---------------- fused patchify + LN1 + int8 fake-quant + GEMM + LN2 + posemb ----------
// grid: 2048 blocks = (b, gh); each block = 32 tokens x 1024 cols.
// 512 threads = 8 waves (2 wm x 4 wn). Wave tile: 16 rows x 256 cols (2 halves x 8 frags).
// LDS (46208 B dynamic):
//   U    [0,      32768)  : x-stage (18816 B fp32) then B col-half slices (32 KB)
//   A16  [32768,  45056)  : quantized A, [c24(24)][r(32)][j(8)] f16
//   stats[45056,  46080)  : [rloc(32)][wn(4)][{sum,sq}] f32
//   sxl  [46080,  46208)  : per-token dequant scale f32
__global__ __launch_bounds__(512, 4) void fused(
    const float* __restrict__ x, const float* __restrict__ g1,
    const float* __restrict__ b1, const _Float16* __restrict__ Wq,
    const float* __restrict__ swbuf, const float* __restrict__ bproj,
    const float* __restrict__ g2, const float* __restrict__ b2,
    const float* __restrict__ pe, float* __restrict__ out) {
    extern __shared__ char lds[];
    float*    xs    = (float*)lds;
    half8*    Bl8   = (half8*)lds;
    _Float16* A16   = (_Float16*)(lds + 32768);
    const half8* A8 = (const half8*)(lds + 32768);
    float*    stats = (float*)(lds + 45056);
    float*    sxl   = (float*)(lds + 46080);

    int tid = threadIdx.x;
    int wave = tid >> 6, lane = tid & 63;
    int wm = wave >> 2, wn = wave & 3;
    int l15 = lane & 15, lg = lane >> 4;
    int blk = blockIdx.x;
    int b = blk >> 5, gh = blk & 31;

    // ---- phase 0: coalesced x stage (21 rows of 224 floats, as float4) ----
    const f32x4b* x4 = (const f32x4b*)x;
    int base4 = b * 37632 + gh * 392;             // (b*150528 + gh*1568)/4
    f32x4b* xs4 = (f32x4b*)xs;
#pragma unroll
    for (int it = 0; it < 3; it++) {
        int j = tid + it * 512;
        if (j < 1176) {
            int c = j / 392, i4 = j - c * 392;
            xs4[c * 392 + i4] = x4[base4 + c * 12544 + i4];
        }
    }
    __syncthreads();

    // ---- phase 1: LN1 + per-token absmax int8 fake-quant -> A16 ----
    {
        int r = tid >> 4, sub = tid & 15;         // token r (=gw), lane-slice sub
        float vals[12];
        float sum = 0.f, sq = 0.f;
#pragma unroll
        for (int i = 0; i < 12; i++) {
            int k = sub + (i << 4);
            float val = 0.f;
            if (k < 147) {
                int c = k % 3, pp = k / 3, p1 = pp / 7, p2 = pp % 7;
                val = xs[c * 1568 + p1 * 224 + r * 7 + p2];
            }
            vals[i] = val;
            sum += val; sq += val * val;
        }
#pragma unroll
        for (int m = 1; m < 16; m <<= 1) {
            sum += __shfl_xor(sum, m);
            sq  += __shfl_xor(sq, m);
        }
        float mu = sum * (1.0f / 147.0f);
        float rstd = rsqrtf(sq * (1.0f / 147.0f) - mu * mu + 1e-5f);
        float amax = 0.f;
#pragma unroll
        for (int i = 0; i < 12; i++) {
            int k = sub + (i << 4);
            if (k < 147) {
                float v = (vals[i] - mu) * rstd * g1[k] + b1[k];
                vals[i] = v;
                amax = fmaxf(amax, fabsf(v));
            }
        }
#pragma unroll
        for (int m = 1; m < 16; m <<= 1) amax = fmaxf(amax, __shfl_xor(amax, m));
        float mx = fmaxf(amax, 1e-5f);
        float sx = 127.0f / mx;
#pragma unroll
        for (int i = 0; i < 12; i++) {
            int k = sub + (i << 4);
            float q = 0.f;
            if (k < 147) q = fminf(fmaxf(rintf(vals[i] * sx), -128.f), 127.f);
            A16[((k >> 3) * 32 + r) * 8 + (k & 7)] = (_Float16)q;
        }
        if (sub == 0) sxl[r] = mx * (1.0f / 127.0f);
    }
    __syncthreads();   // A16 ready; xs no longer needed (U becomes B buffer)

    // ---- phase 2: GEMM, K = 6 slices of 32, cols in 2 halves of 512 ----
    f32x4 acc[16];
#pragma unroll
    for (int i = 0; i < 16; i++) acc[i] = (f32x4)0.f;

    const half8* Wq8 = (const half8*)Wq;
    for (int kk = 0; kk < 6; kk++) {
        half8 a = A8[(kk * 4 + lg) * 32 + wm * 16 + l15];
#pragma unroll
        for (int h = 0; h < 2; h++) {
            // stage 32 KB col-half: [c(4)][d'(512)] half8
#pragma unroll
            for (int it = 0; it < 4; it++) {
                int j = tid + it * 512;           // < 2048
                int c = j >> 9, d = j & 511;
                Bl8[j] = Wq8[(kk * 4 + c) * 1024 + h * 512 + d];
            }
            __syncthreads();
#pragma unroll
            for (int n = 0; n < 8; n++) {
                half8 bf = Bl8[lg * 512 + wn * 128 + n * 16 + l15];
                acc[h * 8 + n] = __builtin_amdgcn_mfma_f32_16x16x32_f16(a, bf, acc[h * 8 + n], 0, 0, 0);
            }
            __syncthreads();
        }
    }

    // ---- phase 3: epilogue — dequant + bias, LN2 over 1024 cols, + posemb ----
    float inv_sw = swbuf[0];
    float sc[4];
    int rloc[4];
#pragma unroll
    for (int rr = 0; rr < 4; rr++) {
        rloc[rr] = wm * 16 + lg * 4 + rr;
        sc[rr] = sxl[rloc[rr]] * inv_sw;
    }
    float s[4] = {0.f, 0.f, 0.f, 0.f}, q[4] = {0.f, 0.f, 0.f, 0.f};
#pragma unroll
    for (int h = 0; h < 2; h++)
#pragma unroll
    for (int n = 0; n < 8; n++) {
        int idx = h * 8 + n;
        int col = h * 512 + wn * 128 + n * 16 + l15;
        float bp = bproj[col];
#pragma unroll
        for (int rr = 0; rr < 4; rr++) {
            float v = acc[idx][rr] * sc[rr] + bp;
            acc[idx][rr] = v;
            s[rr] += v; q[rr] += v * v;
        }
    }
#pragma unroll
    for (int m = 1; m < 16; m <<= 1) {
#pragma unroll
        for (int rr = 0; rr < 4; rr++) {
            s[rr] += __shfl_xor(s[rr], m);
            q[rr] += __shfl_xor(q[rr], m);
        }
    }
    if (l15 == 0) {
#pragma unroll
        for (int rr = 0; rr < 4; rr++) {
            stats[(rloc[rr] * 4 + wn) * 2 + 0] = s[rr];
            stats[(rloc[rr] * 4 + wn) * 2 + 1] = q[rr];
        }
    }
    __syncthreads();

    float mean[4], rstd2[4];
#pragma unroll
    for (int rr = 0; rr < 4; rr++) {
        float st = 0.f, qt = 0.f;
#pragma unroll
        for (int w = 0; w < 4; w++) {
            st += stats[(rloc[rr] * 4 + w) * 2 + 0];
            qt += stats[(rloc[rr] * 4 + w) * 2 + 1];
        }
        float mu = st * (1.0f / 1024.0f);
        mean[rr] = mu;
        rstd2[rr] = rsqrtf(qt * (1.0f / 1024.0f) - mu * mu + 1e-5f);
    }

#pragma unroll
    for (int h = 0; h < 2; h++)
#pragma unroll
    for (int n = 0; n < 8; n++) {
        int idx = h * 8 + n;
        int col = h * 512 + wn * 128 + n * 16 + l15;
        float gg = g2[col], bb = b2[col];
#pragma unroll
        for (int rr = 0; rr < 4; rr++) {
            int row = blk * 32 + rloc[rr];
            int nimg = gh * 32 + rloc[rr];
            float o = (acc[idx][rr] - mean[rr]) * rstd2[rr] * gg + bb + pe[nimg * 1024 + col];
            out[(size_t)row * 1024 + col] = o;
        }
    }
}

extern "C" void kernel_launch(void* const* d_in, const int* in_sizes, int n_in,
                              void* d_out, int out_size, void* d_ws, size_t ws_size,
                              hipStream_t stream) {
    const float* x     = (const float*)d_in[0];
    const float* ln1_g = (const float*)d_in[1];
    const float* ln1_b = (const float*)d_in[2];
    const float* W     = (const float*)d_in[3];
    const float* bproj = (const float*)d_in[4];
    const float* ln2_g = (const float*)d_in[5];
    const float* ln2_b = (const float*)d_in[6];
    float* out = (float*)d_out;

    // workspace layout
    char* ws = (char*)d_ws;
    float*    pe    = (float*)ws;                              // 4 MB
    _Float16* Wq    = (_Float16*)(ws + (4u << 20));            // 393,216 B
    float*    part  = (float*)(ws + (4u << 20) + 393216u);     // 147 floats
    float*    swbuf = part + 160;

    pe_gen<<<4096, 256, 0, stream>>>(pe);
    wabs<<<147, 256, 0, stream>>>(W, part);
    wquant<<<768, 256, 0, stream>>>(W, part, swbuf, Wq);
    fused<<<2048, 512, 46208, stream>>>(x, ln1_g, ln1_b, Wq, swbuf, bproj,
                                        ln2_g, ln2_b, pe, out);
}